// Round 1
// baseline (142.125 us; speedup 1.0000x reference)
//
#include <hip/hip_runtime.h>
#include <math.h>

#define B_ROWS 8192
#define DIMS   256
#define ATTRS  4
#define TI 64
#define TJ 64
#define KC 32
#define LDA (TI + 4)   // pad keeps float4 alignment (4-word) and bank spread

constexpr float INV_T = 1.0f / 0.07f;

// ---------------- kernel 1: L2-normalize rows + flag all-ones-attribute rows --
__global__ __launch_bounds__(256)
void normalize_flag_kernel(const float* __restrict__ z,
                           const float* __restrict__ attr,
                           float* __restrict__ zn,
                           int* __restrict__ flags,
                           int* __restrict__ onelist,
                           int* __restrict__ count) {
    const int row = blockIdx.x;
    const int t = threadIdx.x;            // 256 threads, one per dim
    float v = z[(size_t)row * DIMS + t];
    float ss = v * v;
    #pragma unroll
    for (int o = 32; o > 0; o >>= 1) ss += __shfl_down(ss, o, 64);
    __shared__ float wsum[4];
    const int wave = t >> 6, lane = t & 63;
    if (lane == 0) wsum[wave] = ss;
    __syncthreads();
    if (t == 0) wsum[0] = wsum[0] + wsum[1] + wsum[2] + wsum[3];
    __syncthreads();
    const float norm = fmaxf(sqrtf(wsum[0]), 1e-12f);
    zn[(size_t)row * DIMS + t] = v / norm;
    if (t == 0) {
        const float* a = attr + (size_t)row * ATTRS;
        const bool one = (a[0] == 1.0f) && (a[1] == 1.0f) && (a[2] == 1.0f) && (a[3] == 1.0f);
        flags[row] = one ? 1 : 0;
        if (one) {
            int slot = atomicAdd(count, 1);
            onelist[slot] = row;
        }
    }
}

// ---------------- kernel 2: fused (valid-rows x all-cols) dot + exp + row sums -
__global__ __launch_bounds__(256)
void simloss_gemm_kernel(const float* __restrict__ zn,
                         const int* __restrict__ flags,
                         const int* __restrict__ onelist,
                         const int* __restrict__ count,
                         float* __restrict__ pos_sum,
                         float* __restrict__ all_sum) {
    const int n = *count;
    const int rowBase = blockIdx.y * TI;
    if (rowBase >= n) return;             // inactive row tiles exit fast
    const int colBase = blockIdx.x * TJ;

    __shared__ __align__(16) float Ast[KC][LDA];  // K-major: Ast[k][i]
    __shared__ __align__(16) float Bst[KC][LDA];  // K-major: Bst[k][j]
    __shared__ int gidx[TI];
    __shared__ int fl[TJ];

    const int t = threadIdx.x;
    if (t < TI) {
        const int slot = rowBase + t;
        gidx[t] = (slot < n) ? onelist[slot] : -1;
    }
    if (t < TJ) fl[t] = flags[colBase + t];
    // (first __syncthreads below covers these)

    const int tx = t & 15, ty = t >> 4;
    float c[4][4];
    #pragma unroll
    for (int a = 0; a < 4; a++)
        #pragma unroll
        for (int b = 0; b < 4; b++) c[a][b] = 0.0f;

    for (int k0 = 0; k0 < DIMS; k0 += KC) {
        __syncthreads();                  // protect prior-iter LDS reads + gidx/fl on iter 0
        // stage A (gathered valid rows) and B (contiguous cols): 64 rows x 32 k each
        #pragma unroll
        for (int l = 0; l < 2; l++) {
            const int idx = t * 2 + l;    // 0..511
            const int r   = idx >> 3;     // local row 0..63
            const int f4  = idx & 7;      // float4 index within 32-k chunk
            const int g = gidx[r];
            float4 v = make_float4(0.f, 0.f, 0.f, 0.f);
            if (g >= 0)
                v = *reinterpret_cast<const float4*>(&zn[(size_t)g * DIMS + k0 + f4 * 4]);
            Ast[f4 * 4 + 0][r] = v.x;
            Ast[f4 * 4 + 1][r] = v.y;
            Ast[f4 * 4 + 2][r] = v.z;
            Ast[f4 * 4 + 3][r] = v.w;
            const int j = colBase + r;
            const float4 w = *reinterpret_cast<const float4*>(&zn[(size_t)j * DIMS + k0 + f4 * 4]);
            Bst[f4 * 4 + 0][r] = w.x;
            Bst[f4 * 4 + 1][r] = w.y;
            Bst[f4 * 4 + 2][r] = w.z;
            Bst[f4 * 4 + 3][r] = w.w;
        }
        __syncthreads();
        #pragma unroll
        for (int k = 0; k < KC; k++) {
            const float4 av = *reinterpret_cast<const float4*>(&Ast[k][ty * 4]);
            const float4 bv = *reinterpret_cast<const float4*>(&Bst[k][tx * 4]);
            const float ar[4] = {av.x, av.y, av.z, av.w};
            const float br[4] = {bv.x, bv.y, bv.z, bv.w};
            #pragma unroll
            for (int a = 0; a < 4; a++)
                #pragma unroll
                for (int b = 0; b < 4; b++)
                    c[a][b] = fmaf(ar[a], br[b], c[a][b]);
        }
    }

    // epilogue: exp, diagonal mask, per-row partial sums
    float rowAll[4], rowPos[4];
    #pragma unroll
    for (int a = 0; a < 4; a++) { rowAll[a] = 0.f; rowPos[a] = 0.f; }
    #pragma unroll
    for (int a = 0; a < 4; a++) {
        const int g = gidx[ty * 4 + a];
        #pragma unroll
        for (int b = 0; b < 4; b++) {
            const int j = colBase + tx * 4 + b;
            const float e = __expf(c[a][b] * INV_T);
            const float ev = (j != g) ? e : 0.0f;
            rowAll[a] += ev;
            rowPos[a] += fl[tx * 4 + b] ? ev : 0.0f;
        }
    }
    // reduce across the 16 lanes sharing ty (lanes are contiguous within a wave)
    #pragma unroll
    for (int off = 8; off > 0; off >>= 1) {
        #pragma unroll
        for (int a = 0; a < 4; a++) {
            rowAll[a] += __shfl_down(rowAll[a], off, 16);
            rowPos[a] += __shfl_down(rowPos[a], off, 16);
        }
    }
    if (tx == 0) {
        #pragma unroll
        for (int a = 0; a < 4; a++) {
            const int slot = rowBase + ty * 4 + a;
            if (slot < n) {
                atomicAdd(&all_sum[slot], rowAll[a]);
                atomicAdd(&pos_sum[slot], rowPos[a]);
            }
        }
    }
}

// ---------------- kernel 3: final loss -----------------------------------------
__global__ __launch_bounds__(256)
void finalize_kernel(const float* __restrict__ pos_sum,
                     const float* __restrict__ all_sum,
                     const int* __restrict__ count,
                     float* __restrict__ out) {
    const int n = *count;
    const int t = threadIdx.x;
    float local = 0.0f;
    if (n >= 2) {
        for (int i = t; i < n; i += 256)
            local += logf(all_sum[i]) - logf(pos_sum[i]);
    }
    #pragma unroll
    for (int o = 32; o > 0; o >>= 1) local += __shfl_down(local, o, 64);
    __shared__ float wsum[4];
    const int wave = t >> 6, lane = t & 63;
    if (lane == 0) wsum[wave] = local;
    __syncthreads();
    if (t == 0) {
        const float tot = wsum[0] + wsum[1] + wsum[2] + wsum[3];
        out[0] = (n >= 2) ? (tot / (float)n) : 0.0f;
    }
}

// ---------------- launcher -----------------------------------------------------
extern "C" void kernel_launch(void* const* d_in, const int* in_sizes, int n_in,
                              void* d_out, int out_size, void* d_ws, size_t ws_size,
                              hipStream_t stream) {
    // inputs: [0] z_original (unused), [1] z_flowed, [2] attributes
    const float* z_flowed = (const float*)d_in[1];
    const float* attr     = (const float*)d_in[2];
    float* out = (float*)d_out;

    char* ws = (char*)d_ws;
    int*   count    = (int*)ws;                               // offset 0
    int*   flags    = (int*)(ws + 64);                        // B ints
    int*   onelist  = flags + B_ROWS;                         // B ints
    float* pos_sum  = (float*)(onelist + B_ROWS);             // B floats
    float* all_sum  = pos_sum + B_ROWS;                       // B floats
    float* zn       = all_sum + B_ROWS;                       // B*D floats (8 MB)

    // zero count + pos_sum + all_sum (flags/onelist fully overwritten or guarded)
    const size_t zero_bytes = 64 + (size_t)4 * B_ROWS * sizeof(int);
    hipMemsetAsync(ws, 0, zero_bytes, stream);

    normalize_flag_kernel<<<B_ROWS, 256, 0, stream>>>(z_flowed, attr, zn, flags, onelist, count);

    dim3 grid(B_ROWS / TJ, B_ROWS / TI);  // 128 x 128; row tiles beyond count exit early
    simloss_gemm_kernel<<<grid, 256, 0, stream>>>(zn, flags, onelist, count, pos_sum, all_sum);

    finalize_kernel<<<1, 256, 0, stream>>>(pos_sum, all_sum, count, out);
}

// Round 2
// 112.914 us; speedup vs baseline: 1.2587x; 1.2587x over previous
//
#include <hip/hip_runtime.h>
#include <math.h>

#define BROWS 8192
#define DIMS  256
#define ATTRS 4
#define TI 128
#define TJ 128
#define BK 32
#define LDK 40   // padded k-stride in bf16 elems (80 B = 20 words -> 2-way banks, free)

typedef __bf16 bf16x8 __attribute__((ext_vector_type(8)));
typedef __bf16 bf16x4 __attribute__((ext_vector_type(4)));
typedef float  f32x4  __attribute__((ext_vector_type(4)));

constexpr float INV_T = 1.0f / 0.07f;

// ---------- kernel 1: normalize rows -> bf16 hi/lo split + flag all-ones rows --
__global__ __launch_bounds__(256)
void prep_kernel(const float* __restrict__ z, const float* __restrict__ attr,
                 __bf16* __restrict__ zh, __bf16* __restrict__ zl,
                 int* __restrict__ flags, int* __restrict__ onelist,
                 int* __restrict__ count) {
    const int t = threadIdx.x;
    const int lane = t & 63;
    const int row = blockIdx.x * 4 + (t >> 6);   // one wave per row

    const float4 v = *reinterpret_cast<const float4*>(&z[(size_t)row * DIMS + lane * 4]);
    float ss = v.x * v.x + v.y * v.y + v.z * v.z + v.w * v.w;
    #pragma unroll
    for (int m = 32; m >= 1; m >>= 1) ss += __shfl_xor(ss, m);
    const float norm = fmaxf(sqrtf(ss), 1e-12f);

    const float x0 = v.x / norm, x1 = v.y / norm, x2 = v.z / norm, x3 = v.w / norm;
    const __bf16 h0 = (__bf16)x0, h1 = (__bf16)x1, h2 = (__bf16)x2, h3 = (__bf16)x3;
    bf16x4 hv = {h0, h1, h2, h3};
    bf16x4 lv = {(__bf16)(x0 - (float)h0), (__bf16)(x1 - (float)h1),
                 (__bf16)(x2 - (float)h2), (__bf16)(x3 - (float)h3)};
    *reinterpret_cast<bf16x4*>(&zh[(size_t)row * DIMS + lane * 4]) = hv;
    *reinterpret_cast<bf16x4*>(&zl[(size_t)row * DIMS + lane * 4]) = lv;

    if (lane == 0) {
        const float4 a = *reinterpret_cast<const float4*>(&attr[(size_t)row * ATTRS]);
        const bool one = (a.x == 1.0f) && (a.y == 1.0f) && (a.z == 1.0f) && (a.w == 1.0f);
        flags[row] = one ? 1 : 0;
        if (one) onelist[atomicAdd(count, 1)] = row;
    }
}

// ---------- kernel 2: split-bf16 MFMA GEMM (valid rows x all cols) + fused epilogue
__global__ __launch_bounds__(256)
void gemm_kernel(const __bf16* __restrict__ zh, const __bf16* __restrict__ zl,
                 const int* __restrict__ flags, const int* __restrict__ onelist,
                 const int* __restrict__ count,
                 float* __restrict__ pos_sum, float* __restrict__ all_sum) {
    const int n = *count;
    const int rowBase = blockIdx.y * TI;
    if (rowBase >= n) return;                 // dead row-tiles exit before any barrier
    const int colBase = blockIdx.x * TJ;

    __shared__ __align__(16) __bf16 Ah[TI][LDK];
    __shared__ __align__(16) __bf16 Al[TI][LDK];
    __shared__ __align__(16) __bf16 Bh[TJ][LDK];
    __shared__ __align__(16) __bf16 Bl[TJ][LDK];
    __shared__ int gidx[TI];
    __shared__ int fl[TJ];

    const int t = threadIdx.x;
    if (t < TI) {
        const int slot = rowBase + t;
        gidx[t] = (slot < n) ? onelist[slot] : -1;
    } else {
        fl[t - 128] = flags[colBase + (t - 128)];
    }
    __syncthreads();

    const int lane = t & 63;
    const int w = t >> 6;
    const int wr = (w >> 1) * 64;             // wave tile origin within block tile
    const int wc = (w & 1) * 64;
    const int lm = lane & 15;
    const int lq = lane >> 4;

    // staging map: thread covers rows {krow, 64+krow}, 8 bf16 at offset kseg
    const int krow = t >> 2;
    const int kseg = (t & 3) * 8;
    const int g0 = gidx[krow];
    const int g1 = gidx[64 + krow];
    const size_t arow0 = (size_t)((g0 < 0) ? 0 : g0) * DIMS;
    const size_t arow1 = (size_t)((g1 < 0) ? 0 : g1) * DIMS;
    const size_t brow0 = (size_t)(colBase + krow) * DIMS;
    const size_t brow1 = (size_t)(colBase + 64 + krow) * DIMS;

    f32x4 acc[4][4];
    #pragma unroll
    for (int a = 0; a < 4; a++)
        #pragma unroll
        for (int b = 0; b < 4; b++)
            acc[a][b] = (f32x4){0.f, 0.f, 0.f, 0.f};

    for (int k0 = 0; k0 < DIMS; k0 += BK) {
        __syncthreads();                      // protect prior-iter LDS reads
        *reinterpret_cast<bf16x8*>(&Ah[krow][kseg])      = *reinterpret_cast<const bf16x8*>(&zh[arow0 + k0 + kseg]);
        *reinterpret_cast<bf16x8*>(&Al[krow][kseg])      = *reinterpret_cast<const bf16x8*>(&zl[arow0 + k0 + kseg]);
        *reinterpret_cast<bf16x8*>(&Ah[64 + krow][kseg]) = *reinterpret_cast<const bf16x8*>(&zh[arow1 + k0 + kseg]);
        *reinterpret_cast<bf16x8*>(&Al[64 + krow][kseg]) = *reinterpret_cast<const bf16x8*>(&zl[arow1 + k0 + kseg]);
        *reinterpret_cast<bf16x8*>(&Bh[krow][kseg])      = *reinterpret_cast<const bf16x8*>(&zh[brow0 + k0 + kseg]);
        *reinterpret_cast<bf16x8*>(&Bl[krow][kseg])      = *reinterpret_cast<const bf16x8*>(&zl[brow0 + k0 + kseg]);
        *reinterpret_cast<bf16x8*>(&Bh[64 + krow][kseg]) = *reinterpret_cast<const bf16x8*>(&zh[brow1 + k0 + kseg]);
        *reinterpret_cast<bf16x8*>(&Bl[64 + krow][kseg]) = *reinterpret_cast<const bf16x8*>(&zl[brow1 + k0 + kseg]);
        __syncthreads();

        bf16x8 ah[4], al[4], bh[4], bl[4];
        #pragma unroll
        for (int a = 0; a < 4; a++) {
            const int r = wr + a * 16 + lm;
            ah[a] = *reinterpret_cast<const bf16x8*>(&Ah[r][lq * 8]);
            al[a] = *reinterpret_cast<const bf16x8*>(&Al[r][lq * 8]);
        }
        #pragma unroll
        for (int b = 0; b < 4; b++) {
            const int c = wc + b * 16 + lm;
            bh[b] = *reinterpret_cast<const bf16x8*>(&Bh[c][lq * 8]);
            bl[b] = *reinterpret_cast<const bf16x8*>(&Bl[c][lq * 8]);
        }
        #pragma unroll
        for (int a = 0; a < 4; a++)
            #pragma unroll
            for (int b = 0; b < 4; b++) {
                acc[a][b] = __builtin_amdgcn_mfma_f32_16x16x32_bf16(ah[a], bh[b], acc[a][b], 0, 0, 0);
                acc[a][b] = __builtin_amdgcn_mfma_f32_16x16x32_bf16(ah[a], bl[b], acc[a][b], 0, 0, 0);
                acc[a][b] = __builtin_amdgcn_mfma_f32_16x16x32_bf16(al[a], bh[b], acc[a][b], 0, 0, 0);
            }
    }

    // ---------------- fused epilogue: exp, masks, per-row sums ------------------
    int flb[4];
    #pragma unroll
    for (int b = 0; b < 4; b++) flb[b] = fl[wc + b * 16 + lm];
    const int jg0 = colBase + wc + lm;

    #pragma unroll
    for (int a = 0; a < 4; a++) {
        #pragma unroll
        for (int r = 0; r < 4; r++) {
            const int il = wr + a * 16 + lq * 4 + r;  // local row this lane's reg r holds
            const int g = gidx[il];                    // global row id (for diag mask)
            float sAll = 0.f, sPos = 0.f;
            #pragma unroll
            for (int b = 0; b < 4; b++) {
                const int jg = jg0 + b * 16;
                float e = __expf(acc[a][b][r] * INV_T);
                if (jg == g) e = 0.f;                  // zero the diagonal
                sAll += e;
                if (flb[b]) sPos += e;
            }
            #pragma unroll
            for (int m = 8; m >= 1; m >>= 1) {         // reduce across the 16-col lanes
                sAll += __shfl_xor(sAll, m);
                sPos += __shfl_xor(sPos, m);
            }
            if (lm == 0) {
                const int slot = rowBase + il;
                if (slot < n) {
                    atomicAdd(&all_sum[slot], sAll);
                    atomicAdd(&pos_sum[slot], sPos);
                }
            }
        }
    }
}

// ---------- kernel 3: final loss ------------------------------------------------
__global__ __launch_bounds__(256)
void finalize_kernel(const float* __restrict__ pos_sum,
                     const float* __restrict__ all_sum,
                     const int* __restrict__ count,
                     float* __restrict__ out) {
    const int n = *count;
    const int t = threadIdx.x;
    float local = 0.0f;
    if (n >= 2) {
        for (int i = t; i < n; i += 256)
            local += logf(all_sum[i]) - logf(pos_sum[i]);
    }
    #pragma unroll
    for (int o = 32; o >= 1; o >>= 1) local += __shfl_down(local, o, 64);
    __shared__ float wsum[4];
    const int wave = t >> 6, lane = t & 63;
    if (lane == 0) wsum[wave] = local;
    __syncthreads();
    if (t == 0) {
        const float tot = wsum[0] + wsum[1] + wsum[2] + wsum[3];
        out[0] = (n >= 2) ? (tot / (float)n) : 0.0f;
    }
}

// ---------- launcher ------------------------------------------------------------
extern "C" void kernel_launch(void* const* d_in, const int* in_sizes, int n_in,
                              void* d_out, int out_size, void* d_ws, size_t ws_size,
                              hipStream_t stream) {
    // inputs: [0] z_original (unused), [1] z_flowed, [2] attributes
    const float* z_flowed = (const float*)d_in[1];
    const float* attr     = (const float*)d_in[2];
    float* out = (float*)d_out;

    char* ws = (char*)d_ws;
    int*    count   = (int*)ws;                          // 64 B slot
    float*  pos_sum = (float*)(ws + 64);                 // B floats
    float*  all_sum = pos_sum + BROWS;                   // B floats
    int*    flags   = (int*)(all_sum + BROWS);           // B ints
    int*    onelist = flags + BROWS;                     // B ints
    __bf16* zh      = (__bf16*)(onelist + BROWS);        // B*D bf16 (4 MB)
    __bf16* zl      = zh + (size_t)BROWS * DIMS;         // B*D bf16 (4 MB)

    // zero count + pos_sum + all_sum (flags/onelist fully written by prep)
    hipMemsetAsync(ws, 0, 64 + (size_t)2 * BROWS * sizeof(float), stream);

    prep_kernel<<<BROWS / 4, 256, 0, stream>>>(z_flowed, attr, zh, zl, flags, onelist, count);

    dim3 grid(BROWS / TJ, BROWS / TI);  // 64 x 64; row tiles beyond count exit early
    gemm_kernel<<<grid, 256, 0, stream>>>(zh, zl, flags, onelist, count, pos_sum, all_sum);

    finalize_kernel<<<1, 256, 0, stream>>>(pos_sum, all_sum, count, out);
}

// Round 3
// 112.033 us; speedup vs baseline: 1.2686x; 1.0079x over previous
//
#include <hip/hip_runtime.h>
#include <math.h>

#define BROWS 8192
#define DIMS  256
#define ATTRS 4
#define TI 128          // valid-row tile
#define TJ 128          // col tile
#define BK 32           // k-chunk (32 bf16 = 64 B = 4 x 16B segs per row)
#define NKIT (DIMS / BK)
#define COLT (BROWS / TJ)   // 64 col tiles
#define GEMM_BLOCKS 256

typedef __bf16 bf16x8 __attribute__((ext_vector_type(8)));
typedef __bf16 bf16x4 __attribute__((ext_vector_type(4)));
typedef float  f32x4  __attribute__((ext_vector_type(4)));

constexpr float INV_T = 1.0f / 0.07f;

// async global->LDS, 16 B per lane. LDS dest semantics: wave-uniform base + lane*16.
__device__ __forceinline__ void async_cp16(void* lds, const void* g) {
    __builtin_amdgcn_global_load_lds(
        (const __attribute__((address_space(1))) unsigned int*)g,
        (__attribute__((address_space(3))) unsigned int*)lds,
        16, 0, 0);
}

// ---------- kernel 1: normalize rows -> bf16 hi/lo split + flags + onelist -----
__global__ __launch_bounds__(256)
void prep_kernel(const float* __restrict__ z, const float* __restrict__ attr,
                 __bf16* __restrict__ zh, __bf16* __restrict__ zl,
                 int* __restrict__ flags, int* __restrict__ onelist,
                 int* __restrict__ count,
                 float* __restrict__ pos_sum, float* __restrict__ all_sum) {
    const int t = threadIdx.x;
    const int lane = t & 63;
    const int row = blockIdx.x * 4 + (t >> 6);   // one wave per row

    const float4 v = *reinterpret_cast<const float4*>(&z[(size_t)row * DIMS + lane * 4]);
    float ss = v.x * v.x + v.y * v.y + v.z * v.z + v.w * v.w;
    #pragma unroll
    for (int m = 32; m >= 1; m >>= 1) ss += __shfl_xor(ss, m);
    const float norm = fmaxf(sqrtf(ss), 1e-12f);

    const float x0 = v.x / norm, x1 = v.y / norm, x2 = v.z / norm, x3 = v.w / norm;
    const __bf16 h0 = (__bf16)x0, h1 = (__bf16)x1, h2 = (__bf16)x2, h3 = (__bf16)x3;
    bf16x4 hv = {h0, h1, h2, h3};
    bf16x4 lv = {(__bf16)(x0 - (float)h0), (__bf16)(x1 - (float)h1),
                 (__bf16)(x2 - (float)h2), (__bf16)(x3 - (float)h3)};
    *reinterpret_cast<bf16x4*>(&zh[(size_t)row * DIMS + lane * 4]) = hv;
    *reinterpret_cast<bf16x4*>(&zl[(size_t)row * DIMS + lane * 4]) = lv;

    if (lane == 0) {
        pos_sum[row] = 0.0f;                     // zero accumulators (ws is poisoned)
        all_sum[row] = 0.0f;
        const float4 a = *reinterpret_cast<const float4*>(&attr[(size_t)row * ATTRS]);
        const bool one = (a.x == 1.0f) && (a.y == 1.0f) && (a.z == 1.0f) && (a.w == 1.0f);
        flags[row] = one ? 1 : 0;
        if (one) onelist[atomicAdd(count, 1)] = row;
    }
}

// ---------- kernel 2: split-bf16 MFMA GEMM, async-LDS dbuf, fused epilogue ------
__global__ __launch_bounds__(256, 2)
void gemm_kernel(const __bf16* __restrict__ zh, const __bf16* __restrict__ zl,
                 const int* __restrict__ flags, const int* __restrict__ onelist,
                 const int* __restrict__ count,
                 float* __restrict__ pos_sum, float* __restrict__ all_sum) {
    const int n = *count;
    const int rowTiles = (n + TI - 1) / TI;
    const int totalTiles = rowTiles * COLT;

    // unpadded (global_load_lds requires lane-contiguous dest); XOR seg-swizzle
    // breaks the 32-word row stride for conflict-free frag reads.
    __shared__ __align__(16) __bf16 sAh[2][TI][BK];   // 16 KB
    __shared__ __align__(16) __bf16 sAl[2][TI][BK];   // 16 KB
    __shared__ __align__(16) __bf16 sBh[2][TJ][BK];   // 16 KB

    const int t = threadIdx.x;
    const int lane = t & 63;
    const int w = t >> 6;
    const int wr = (w >> 1) * 64, wc = (w & 1) * 64;  // wave tile origin
    const int lm = lane & 15, lq = lane >> 4;

    // staging lane constants: each wave-instr covers 16 rows x 64 B
    const int srow = lane >> 2;                       // row within 16-row group
    const int sseg = (lane & 3) ^ (srow & 3);         // global seg this lane fetches
    const char* zhB = (const char*)zh;
    const char* zlB = (const char*)zl;

    for (int tile = blockIdx.x; tile < totalTiles; tile += gridDim.x) {
        const int rowBase = (tile >> 6) * TI;         // COLT == 64
        const int colBase = (tile & 63) * TJ;

        // per-lane global source byte offsets (row*512 + swizzled seg*16)
        size_t offA[2], offB[2];
        #pragma unroll
        for (int h = 0; h < 2; ++h) {
            const int slot = rowBase + h * 64 + w * 16 + srow;
            const int gA = (slot < n) ? onelist[slot] : 0;
            offA[h] = (size_t)gA * 512 + (size_t)sseg * 16;
            const int gBr = colBase + h * 64 + w * 16 + srow;
            offB[h] = (size_t)gBr * 512 + (size_t)sseg * 16;
        }

        f32x4 acc[4][4];
        #pragma unroll
        for (int a = 0; a < 4; ++a)
            #pragma unroll
            for (int b = 0; b < 4; ++b)
                acc[a][b] = (f32x4){0.f, 0.f, 0.f, 0.f};

        auto stage = [&](int buf, int kbyte) {
            #pragma unroll
            for (int h = 0; h < 2; ++h) {
                const int R0 = h * 64 + w * 16;
                async_cp16((char*)&sAh[buf][R0][0] + lane * 16, zhB + offA[h] + kbyte);
                async_cp16((char*)&sAl[buf][R0][0] + lane * 16, zlB + offA[h] + kbyte);
                async_cp16((char*)&sBh[buf][R0][0] + lane * 16, zhB + offB[h] + kbyte);
            }
        };

        stage(0, 0);
        __syncthreads();                              // drains vmcnt -> buf0 ready

        for (int it = 0; it < NKIT; ++it) {
            const int cur = it & 1;
            if (it + 1 < NKIT) stage(cur ^ 1, (it + 1) * BK * 2);  // issue next chunk first

            bf16x8 ah[4], al[4], bh[4];
            #pragma unroll
            for (int a = 0; a < 4; ++a) {
                const int R = wr + a * 16 + lm;
                const int sw = (lq ^ (R & 3)) * 8;
                ah[a] = *reinterpret_cast<const bf16x8*>(&sAh[cur][R][sw]);
                al[a] = *reinterpret_cast<const bf16x8*>(&sAl[cur][R][sw]);
            }
            #pragma unroll
            for (int b = 0; b < 4; ++b) {
                const int C = wc + b * 16 + lm;
                const int sw = (lq ^ (C & 3)) * 8;
                bh[b] = *reinterpret_cast<const bf16x8*>(&sBh[cur][C][sw]);
            }
            #pragma unroll
            for (int a = 0; a < 4; ++a)
                #pragma unroll
                for (int b = 0; b < 4; ++b) {
                    acc[a][b] = __builtin_amdgcn_mfma_f32_16x16x32_bf16(ah[a], bh[b], acc[a][b], 0, 0, 0);
                    acc[a][b] = __builtin_amdgcn_mfma_f32_16x16x32_bf16(al[a], bh[b], acc[a][b], 0, 0, 0);
                }
            __syncthreads();   // readers done before next-iter overwrite; drains next loads
        }

        // -------- fused epilogue: exp, diag/pos masks, per-row sums, atomics ----
        int flb[4];
        #pragma unroll
        for (int b = 0; b < 4; ++b) flb[b] = flags[colBase + wc + b * 16 + lm];
        const int jg0 = colBase + wc + lm;

        #pragma unroll
        for (int a = 0; a < 4; ++a) {
            #pragma unroll
            for (int r = 0; r < 4; ++r) {
                const int il = wr + a * 16 + lq * 4 + r;  // C/D: col=lm, row=lq*4+r
                const int slot = rowBase + il;
                const int g = (slot < n) ? onelist[slot] : -1;
                float sAll = 0.f, sPos = 0.f;
                #pragma unroll
                for (int b = 0; b < 4; ++b) {
                    float e = __expf(acc[a][b][r] * INV_T);
                    if (jg0 + b * 16 == g) e = 0.f;       // zero diagonal
                    sAll += e;
                    if (flb[b]) sPos += e;
                }
                #pragma unroll
                for (int m = 8; m >= 1; m >>= 1) {
                    sAll += __shfl_xor(sAll, m);
                    sPos += __shfl_xor(sPos, m);
                }
                if (lm == 0 && slot < n) {
                    atomicAdd(&all_sum[slot], sAll);
                    atomicAdd(&pos_sum[slot], sPos);
                }
            }
        }
        // no barrier needed: next tile's stage(0,..) targets buf0, last read at it=6,
        // already fenced by the it=7 __syncthreads above.
    }
}

// ---------- kernel 3: final loss ------------------------------------------------
__global__ __launch_bounds__(256)
void finalize_kernel(const float* __restrict__ pos_sum,
                     const float* __restrict__ all_sum,
                     const int* __restrict__ count,
                     float* __restrict__ out) {
    const int n = *count;
    const int t = threadIdx.x;
    float local = 0.0f;
    if (n >= 2) {
        for (int i = t; i < n; i += 256)
            local += logf(all_sum[i]) - logf(pos_sum[i]);
    }
    #pragma unroll
    for (int o = 32; o >= 1; o >>= 1) local += __shfl_down(local, o, 64);
    __shared__ float wsum[4];
    const int wave = t >> 6, lane = t & 63;
    if (lane == 0) wsum[wave] = local;
    __syncthreads();
    if (t == 0) {
        const float tot = wsum[0] + wsum[1] + wsum[2] + wsum[3];
        out[0] = (n >= 2) ? (tot / (float)n) : 0.0f;
    }
}

// ---------- launcher ------------------------------------------------------------
extern "C" void kernel_launch(void* const* d_in, const int* in_sizes, int n_in,
                              void* d_out, int out_size, void* d_ws, size_t ws_size,
                              hipStream_t stream) {
    // inputs: [0] z_original (unused), [1] z_flowed, [2] attributes
    const float* z_flowed = (const float*)d_in[1];
    const float* attr     = (const float*)d_in[2];
    float* out = (float*)d_out;

    char* ws = (char*)d_ws;
    int*    count   = (int*)ws;                          // 64 B slot
    float*  pos_sum = (float*)(ws + 64);                 // B floats
    float*  all_sum = pos_sum + BROWS;                   // B floats
    int*    flags   = (int*)(all_sum + BROWS);           // B ints
    int*    onelist = flags + BROWS;                     // B ints
    __bf16* zh      = (__bf16*)(onelist + BROWS);        // B*D bf16 (4 MB), 16B-aligned
    __bf16* zl      = zh + (size_t)BROWS * DIMS;         // B*D bf16 (4 MB)

    hipMemsetAsync(ws, 0, 64, stream);                   // zero count only

    prep_kernel<<<BROWS / 4, 256, 0, stream>>>(z_flowed, attr, zh, zl, flags, onelist,
                                               count, pos_sum, all_sum);

    gemm_kernel<<<GEMM_BLOCKS, 256, 0, stream>>>(zh, zl, flags, onelist, count,
                                                 pos_sum, all_sum);

    finalize_kernel<<<1, 256, 0, stream>>>(pos_sum, all_sum, count, out);
}

// Round 4
// 106.876 us; speedup vs baseline: 1.3298x; 1.0483x over previous
//
#include <hip/hip_runtime.h>
#include <math.h>

#define BROWS 8192
#define DIMS  256
#define ATTRS 4
#define TIR 64           // rows (valid) per tile
#define TJC 128          // cols per tile
#define BK 64            // k-chunk: 64 bf16 = 128 B = 8 x 16B segs per row
#define NKIT (DIMS / BK) // 4
#define COLT (BROWS / TJC)  // 64 col tiles
#define GEMM_BLOCKS 512

typedef __bf16 bf16x8 __attribute__((ext_vector_type(8)));
typedef __bf16 bf16x4 __attribute__((ext_vector_type(4)));
typedef float  f32x4  __attribute__((ext_vector_type(4)));

constexpr float INV_T = 1.0f / 0.07f;

// async global->LDS, 16 B/lane; HW dest = wave-uniform base + lane*16
__device__ __forceinline__ void async_cp16(void* lds, const void* g) {
    __builtin_amdgcn_global_load_lds(
        (const __attribute__((address_space(1))) unsigned int*)g,
        (__attribute__((address_space(3))) unsigned int*)lds,
        16, 0, 0);
}

// ---------- kernel 1: normalize rows -> bf16 + flag all-ones rows --------------
__global__ __launch_bounds__(256)
void prep_kernel(const float* __restrict__ z, const float* __restrict__ attr,
                 __bf16* __restrict__ zh,
                 int* __restrict__ flags, int* __restrict__ onelist,
                 int* __restrict__ count,
                 float* __restrict__ pos_sum, float* __restrict__ all_sum) {
    const int t = threadIdx.x;
    const int lane = t & 63;
    const int row = blockIdx.x * 4 + (t >> 6);   // one wave per row

    const float4 v = *reinterpret_cast<const float4*>(&z[(size_t)row * DIMS + lane * 4]);
    float ss = v.x * v.x + v.y * v.y + v.z * v.z + v.w * v.w;
    #pragma unroll
    for (int m = 32; m >= 1; m >>= 1) ss += __shfl_xor(ss, m);
    const float norm = fmaxf(sqrtf(ss), 1e-12f);

    bf16x4 hv = {(__bf16)(v.x / norm), (__bf16)(v.y / norm),
                 (__bf16)(v.z / norm), (__bf16)(v.w / norm)};
    *reinterpret_cast<bf16x4*>(&zh[(size_t)row * DIMS + lane * 4]) = hv;

    if (lane == 0) {
        pos_sum[row] = 0.0f;                     // ws is poisoned each call
        all_sum[row] = 0.0f;
        const float4 a = *reinterpret_cast<const float4*>(&attr[(size_t)row * ATTRS]);
        const bool one = (a.x == 1.0f) && (a.y == 1.0f) && (a.z == 1.0f) && (a.w == 1.0f);
        flags[row] = one ? 1 : 0;
        if (one) onelist[atomicAdd(count, 1)] = row;
    }
}

// ---------- kernel 2: bf16 MFMA GEMM, async-LDS dbuf, fused epilogue ------------
__global__ __launch_bounds__(256, 2)
void gemm_kernel(const __bf16* __restrict__ zh,
                 const int* __restrict__ flags, const int* __restrict__ onelist,
                 const int* __restrict__ count,
                 float* __restrict__ pos_sum, float* __restrict__ all_sum) {
    const int n = *count;
    const int rowTiles = (n + TIR - 1) / TIR;
    const int totalTiles = rowTiles * COLT;

    __shared__ __align__(16) __bf16 sA[2][TIR][BK];   // 16 KB
    __shared__ __align__(16) __bf16 sB[2][TJC][BK];   // 32 KB

    const int t = threadIdx.x;
    const int lane = t & 63;
    const int w = t >> 6;
    const int wr = (w >> 1) * 32, wc = (w & 1) * 64;  // wave tile origin (32x64)
    const int lm = lane & 15, lq = lane >> 4;

    // staging: each wave-instr covers 8 rows x 128 B; lane -> row j=l>>3, seg l&7.
    // XOR seg swizzle applied on the GLOBAL side (lds dest must stay lane-linear):
    // global seg fetched = (l&7) ^ (l>>3)  -> lane-constant.
    const int srow8 = lane >> 3;
    const size_t sgb = (size_t)(((lane & 7) ^ srow8) * 16);
    const char* zhB = (const char*)zh;

    for (int tile = blockIdx.x; tile < totalTiles; tile += gridDim.x) {
        const int rowBase = (tile >> 6) * TIR;        // COLT == 64
        const int colBase = (tile & 63) * TJC;

        size_t aOff[2], bOff[4];
        #pragma unroll
        for (int h = 0; h < 2; ++h) {
            const int slot = rowBase + w * 16 + h * 8 + srow8;
            const int g = (slot < n) ? onelist[slot] : 0;
            aOff[h] = (size_t)g * 512 + sgb;
        }
        #pragma unroll
        for (int h = 0; h < 4; ++h) {
            const int r = colBase + w * 32 + h * 8 + srow8;
            bOff[h] = (size_t)r * 512 + sgb;
        }

        f32x4 acc[2][4];
        #pragma unroll
        for (int a = 0; a < 2; ++a)
            #pragma unroll
            for (int b = 0; b < 4; ++b)
                acc[a][b] = (f32x4){0.f, 0.f, 0.f, 0.f};

        auto stage = [&](int buf, int kbyte) {
            #pragma unroll
            for (int h = 0; h < 2; ++h)
                async_cp16((char*)&sA[buf][w * 16 + h * 8][0] + lane * 16,
                           zhB + aOff[h] + kbyte);
            #pragma unroll
            for (int h = 0; h < 4; ++h)
                async_cp16((char*)&sB[buf][w * 32 + h * 8][0] + lane * 16,
                           zhB + bOff[h] + kbyte);
        };

        stage(0, 0);
        __syncthreads();                              // buf0 landed

        for (int it = 0; it < NKIT; ++it) {
            const int cur = it & 1;
            if (it + 1 < NKIT) stage(cur ^ 1, (it + 1) * BK * 2);

            const int segx = lm & 7;                  // R&7 == lm&7 for all frags
            #pragma unroll
            for (int ks = 0; ks < 2; ++ks) {
                bf16x8 af[2], bf_[4];
                #pragma unroll
                for (int a = 0; a < 2; ++a) {
                    const int R = wr + a * 16 + lm;
                    af[a] = *reinterpret_cast<const bf16x8*>(
                        &sA[cur][R][((ks * 4 + lq) ^ segx) * 8]);
                }
                #pragma unroll
                for (int b = 0; b < 4; ++b) {
                    const int C = wc + b * 16 + lm;
                    bf_[b] = *reinterpret_cast<const bf16x8*>(
                        &sB[cur][C][((ks * 4 + lq) ^ segx) * 8]);
                }
                #pragma unroll
                for (int a = 0; a < 2; ++a)
                    #pragma unroll
                    for (int b = 0; b < 4; ++b)
                        acc[a][b] = __builtin_amdgcn_mfma_f32_16x16x32_bf16(
                            af[a], bf_[b], acc[a][b], 0, 0, 0);
            }
            __syncthreads();   // readers done before overwrite; drains next loads
        }

        // -------- fused epilogue: exp, diag/pos masks, per-row sums, atomics ----
        int flb[4];
        #pragma unroll
        for (int b = 0; b < 4; ++b) flb[b] = flags[colBase + wc + b * 16 + lm];
        const int jg0 = colBase + wc + lm;

        #pragma unroll
        for (int a = 0; a < 2; ++a) {
            #pragma unroll
            for (int r = 0; r < 4; ++r) {
                const int il = wr + a * 16 + lq * 4 + r;   // C/D: col=lm, row=lq*4+r
                const int slot = rowBase + il;
                const int g = (slot < n) ? onelist[slot] : -1;
                float sAll = 0.f, sPos = 0.f;
                #pragma unroll
                for (int b = 0; b < 4; ++b) {
                    float e = __expf(acc[a][b][r] * INV_T);
                    if (jg0 + b * 16 == g) e = 0.f;        // zero diagonal
                    sAll += e;
                    if (flb[b]) sPos += e;
                }
                #pragma unroll
                for (int m = 8; m >= 1; m >>= 1) {
                    sAll += __shfl_xor(sAll, m);
                    sPos += __shfl_xor(sPos, m);
                }
                if (lm == 0 && slot < n) {
                    atomicAdd(&all_sum[slot], sAll);
                    atomicAdd(&pos_sum[slot], sPos);
                }
            }
        }
        // next tile's stage(0,..) writes buf0; last buf0 read (it=2) already fenced
        // by the it=3 barrier above.
    }
}

// ---------- kernel 3: final loss ------------------------------------------------
__global__ __launch_bounds__(256)
void finalize_kernel(const float* __restrict__ pos_sum,
                     const float* __restrict__ all_sum,
                     const int* __restrict__ count,
                     float* __restrict__ out) {
    const int n = *count;
    const int t = threadIdx.x;
    float local = 0.0f;
    if (n >= 2) {
        for (int i = t; i < n; i += 256)
            local += logf(all_sum[i]) - logf(pos_sum[i]);
    }
    #pragma unroll
    for (int o = 32; o >= 1; o >>= 1) local += __shfl_down(local, o, 64);
    __shared__ float wsum[4];
    const int wave = t >> 6, lane = t & 63;
    if (lane == 0) wsum[wave] = local;
    __syncthreads();
    if (t == 0) {
        const float tot = wsum[0] + wsum[1] + wsum[2] + wsum[3];
        out[0] = (n >= 2) ? (tot / (float)n) : 0.0f;
    }
}

// ---------- launcher ------------------------------------------------------------
extern "C" void kernel_launch(void* const* d_in, const int* in_sizes, int n_in,
                              void* d_out, int out_size, void* d_ws, size_t ws_size,
                              hipStream_t stream) {
    // inputs: [0] z_original (unused), [1] z_flowed, [2] attributes
    const float* z_flowed = (const float*)d_in[1];
    const float* attr     = (const float*)d_in[2];
    float* out = (float*)d_out;

    char* ws = (char*)d_ws;
    int*    count   = (int*)ws;                          // 64 B slot
    float*  pos_sum = (float*)(ws + 64);                 // B floats
    float*  all_sum = pos_sum + BROWS;                   // B floats
    int*    flags   = (int*)(all_sum + BROWS);           // B ints
    int*    onelist = flags + BROWS;                     // B ints
    __bf16* zh      = (__bf16*)(onelist + BROWS);        // B*D bf16 (4 MB), 16B-aligned

    hipMemsetAsync(ws, 0, 64, stream);                   // zero count only

    prep_kernel<<<BROWS / 4, 256, 0, stream>>>(z_flowed, attr, zh, flags, onelist,
                                               count, pos_sum, all_sum);

    gemm_kernel<<<GEMM_BLOCKS, 256, 0, stream>>>(zh, flags, onelist, count,
                                                 pos_sum, all_sum);

    finalize_kernel<<<1, 256, 0, stream>>>(pos_sum, all_sum, count, out);
}